// Round 12
// baseline (167.442 us; speedup 1.0000x reference)
//
#include <hip/hip_runtime.h>
#include <hip/hip_bf16.h>
#include <stdint.h>

// SequentialMLP: E=8, H=1024, F=1024, T=16384, Tpe=2048
#define T_TOK 16384
#define H_DIM 1024
#define F_DIM 1024
#define E_NUM 8
#define TPE   2048

typedef unsigned short u16;
typedef __attribute__((ext_vector_type(8))) short bf16x8;   // 8 bf16 (4 VGPRs)
typedef __attribute__((ext_vector_type(4))) float f32x4;    // MFMA accumulator
typedef __attribute__((ext_vector_type(8))) u16 u16x8;

__device__ __forceinline__ u16 f2bf(float x) {
  unsigned int u = __float_as_uint(x);
  u = (u + 0x7fffu + ((u >> 16) & 1u)) >> 16;   // RNE
  return (u16)u;
}

// async global->LDS, 16B per lane. LDS dest = wave-uniform base + lane*16.
#define GLD16(gp, lp)                                                          \
  __builtin_amdgcn_global_load_lds(                                            \
      (const __attribute__((address_space(1))) void*)(gp),                     \
      (__attribute__((address_space(3))) void*)(lp), 16, 0, 0)

// ================================================================= prep pass
// ROUND-12: LDS-free, sync-free transpose. One wave owns 64 cols x 32 rows:
// lane = column; 32 row-reads are wave-coalesced (256-B runs/instr); lane
// converts its column in regs and writes 64 CONSECUTIVE bytes (4x dwordx4
// back-to-back, same cache line -> L2 write-combines). Replay-profile showed
// the r10 LDS version was latency-bound (84MB @ 70us = 1.2TB/s), not BW-bound.
// Blocks: [0,4096) x-cvt | [4096,6144) W1 (4 waves/blk) | [6144,7168) W2.
__global__ __launch_bounds__(256) void prep_all(
    const float* __restrict__ x, const float* __restrict__ W1,
    const float* __restrict__ W2, u16* __restrict__ xbf,
    u16* __restrict__ w1t, u16* __restrict__ w2t) {
  const int bid = blockIdx.x;
  const int t = threadIdx.x;

  if (bid < 4096) {
    // flat cvt: block covers f32 [bid*4096, +4096); thread: 16 consecutive
    size_t base = (size_t)bid * 4096 + (size_t)t * 16;
    const float4* s = (const float4*)(x + base);
    float4 v0 = s[0], v1 = s[1], v2 = s[2], v3 = s[3];
    u16x8 o0, o1;
    o0[0] = f2bf(v0.x); o0[1] = f2bf(v0.y); o0[2] = f2bf(v0.z); o0[3] = f2bf(v0.w);
    o0[4] = f2bf(v1.x); o0[5] = f2bf(v1.y); o0[6] = f2bf(v1.z); o0[7] = f2bf(v1.w);
    o1[0] = f2bf(v2.x); o1[1] = f2bf(v2.y); o1[2] = f2bf(v2.z); o1[3] = f2bf(v2.w);
    o1[4] = f2bf(v3.x); o1[5] = f2bf(v3.y); o1[6] = f2bf(v3.z); o1[7] = f2bf(v3.w);
    *(u16x8*)(xbf + base) = o0;
    *(u16x8*)(xbf + base + 8) = o1;
    return;
  }

  const float* src; u16* dst; int R, C, gw;
  int e, rc, cc;
  const int lane = t & 63;
  const int wid = t >> 6;
  if (bid < 6144) {
    src = W1; dst = w1t; R = H_DIM; C = 2 * F_DIM;
    gw = (bid - 4096) * 4 + wid;          // 8192 waves: e(8) x rc(32) x cc(32)
    e = gw >> 10; int rem = gw & 1023; rc = rem >> 5; cc = rem & 31;
  } else {
    src = W2; dst = w2t; R = F_DIM; C = H_DIM;
    gw = (bid - 6144) * 4 + wid;          // 4096 waves: e(8) x rc(32) x cc(16)
    e = gw >> 9; int rem = gw & 511; rc = rem >> 4; cc = rem & 15;
  }
  const int row0 = rc << 5;               // 32 rows
  const int col0 = cc << 6;               // 64 cols (one per lane)
  const float* s = src + (size_t)e * R * C + (size_t)row0 * C + col0 + lane;
  float v[32];
#pragma unroll
  for (int r = 0; r < 32; ++r) v[r] = s[(size_t)r * C];
  u16* d = dst + (size_t)e * C * R + (size_t)(col0 + lane) * R + row0;
#pragma unroll
  for (int k = 0; k < 4; ++k) {
    u16x8 w;
#pragma unroll
    for (int i = 0; i < 8; ++i) w[i] = f2bf(v[k * 8 + i]);
    *(u16x8*)(d + k * 8) = w;
  }
}

// ====================================================== 256x256 GEMM, 16 waves
// r11 version unchanged (best measured total; GEMM schedule family closed).
// BM=BN=256 / BK=64 / 128KB dbuf LDS, 1024 threads (16 waves, 4Mx4N).
// Ledger: prologue B0(2) A0(2) B1(2) -> vmcnt(2), barrier;
// loop p0: A1q0  p1: A1q1  p3: B0'(2)+vmcnt(2)  p4: A0'q0  p5: A0'q1
// p7: B1'(2)+vmcnt(2). Swizzle byte ^= ((row&7)<<4) via inverse-swizzled
// global source (linear LDS dest, rule 21) + swizzled ds_read offset.

#define DSA2(b, h, ks)                                                         \
  _Pragma("unroll") for (int m2_ = 0; m2_ < 2; ++m2_)                          \
      aF[m2_] = *(const bf16x8*)(sm + (b) * 32768 + aRowBase +                 \
                                 ((h) * 2 + m2_) * 2048 + koff[ks]);

#define DSB4(b, ks)                                                            \
  _Pragma("unroll") for (int n_ = 0; n_ < 4; ++n_)                             \
      bF[n_] = *(const bf16x8*)(sm + 65536 + (b) * 32768 + bRowBase +          \
                                n_ * 2048 + koff[ks]);

#define MFMAP(h)                                                               \
  _Pragma("unroll") for (int n_ = 0; n_ < 4; ++n_)                             \
  _Pragma("unroll") for (int m2_ = 0; m2_ < 2; ++m2_)                          \
      acc[(h) * 2 + m2_][n_] = __builtin_amdgcn_mfma_f32_16x16x32_bf16(        \
          aF[m2_], bF[n_], acc[(h) * 2 + m2_][n_], 0, 0, 0);

#define PF_A(db, q, d) GLD16(aP[q] + (d), sm + (db) * 32768 + (q) * 16384 + tid * 16)
#define PF_B(db, q, d) GLD16(bP[q] + (d), sm + 65536 + (db) * 32768 + (q) * 16384 + tid * 16)

#define VMW(N) asm volatile("s_waitcnt vmcnt(" #N ")" ::: "memory");

#define PHASEK(b, ks, h, PFC, WTC)                                             \
  do {                                                                         \
    DSA2(b, h, ks);                                                            \
    if ((h) == 0) { DSB4(b, ks); }                                             \
    PFC                                                                        \
    __builtin_amdgcn_s_setprio(1);                                             \
    MFMAP(h);                                                                  \
    __builtin_amdgcn_s_setprio(0);                                             \
    WTC                                                                        \
    __builtin_amdgcn_s_barrier();                                              \
  } while (0)

#define KLOOP_BODY                                                             \
  PF_B(0, 0, 0); PF_B(0, 1, 0);                                                \
  PF_A(0, 0, 0); PF_A(0, 1, 0);                                                \
  PF_B(1, 0, 64); PF_B(1, 1, 64);                                              \
  VMW(2)                                                                       \
  __builtin_amdgcn_s_barrier();                                                \
  for (int it = 0; it < 7; ++it) {                                             \
    PHASEK(0, 0, 0, PF_A(1, 0, 64);, );                                        \
    PHASEK(0, 0, 1, PF_A(1, 1, 64);, );                                        \
    PHASEK(0, 1, 0, , );                                                       \
    PHASEK(0, 1, 1, PF_B(0, 0, 128); PF_B(0, 1, 128);, VMW(2));                \
    PHASEK(1, 0, 0, PF_A(0, 0, 128);, );                                       \
    PHASEK(1, 0, 1, PF_A(0, 1, 128);, );                                       \
    PHASEK(1, 1, 0, , );                                                       \
    PHASEK(1, 1, 1, PF_B(1, 0, 192); PF_B(1, 1, 192);, VMW(2));                \
    _Pragma("unroll") for (int q_ = 0; q_ < 2; ++q_) {                         \
      aP[q_] += 128; bP[q_] += 128;                                            \
    }                                                                          \
  }                                                                            \
  PHASEK(0, 0, 0, PF_A(1, 0, 64);, );                                          \
  PHASEK(0, 0, 1, PF_A(1, 1, 64);, );                                          \
  PHASEK(0, 1, 0, , );                                                         \
  PHASEK(0, 1, 1, , VMW(0));                                                   \
  PHASEK(1, 0, 0, , );                                                         \
  PHASEK(1, 0, 1, , );                                                         \
  PHASEK(1, 1, 0, , );                                                         \
  PHASEK(1, 1, 1, , );

// ---------------------------------------------------------------- GEMM1+GLU
__global__ __launch_bounds__(1024) void gemm1_8p(
    const u16* __restrict__ xbf, const u16* __restrict__ w1t,
    const float* __restrict__ b1, const float* __restrict__ probs,
    u16* __restrict__ abf) {
  extern __shared__ char sm[];
  const int tid = threadIdx.x;
  const int lane = tid & 63;
  const int wid = tid >> 6;               // 0..15
  const int wm = wid >> 2, wn = wid & 3;  // 4x4 wave grid, wave tile 64x64
  const int bid = blockIdx.x;
  const int e = bid & 7;          // expert -> XCD pinning (round-robin bid%8)
  const int inner = bid >> 3;
  const int mt = inner >> 3, ct = inner & 7;
  const int tokBase = e * TPE + mt * 256;
  const int c0 = ct * 128;
  const int lrow = lane & 15, lkhi = lane >> 4;

  const u16* aP[2]; const u16* bP[2];
#pragma unroll
  for (int q = 0; q < 2; ++q) {
    int lin = q * 16384 + tid * 16;
    int lg = lin ^ (((lin >> 7) & 7) << 4);   // inverse swizzle (involution)
    int row = lg >> 7, kk = (lg & 127) >> 1;
    aP[q] = xbf + (size_t)(tokBase + row) * H_DIM + kk;
    // B row nn: alternate 32-blocks gate/lin so each wave owns matching pairs
    int col = (((row >> 5) & 1) << 10) + c0 + ((row >> 6) << 5) + (row & 31);
    bP[q] = w1t + (size_t)(e * 2 * F_DIM + col) * H_DIM + kk;
  }
  const int aRowBase = (wm * 64 + lrow) * 128;
  const int bRowBase = (wn * 64 + lrow) * 128;
  int koff[2];
#pragma unroll
  for (int ks = 0; ks < 2; ++ks)
    koff[ks] = ((ks << 6) | (lkhi << 4)) ^ ((lane & 7) << 4);

  f32x4 acc[4][4];
#pragma unroll
  for (int i = 0; i < 4; ++i)
#pragma unroll
    for (int j = 0; j < 4; ++j) acc[i][j] = f32x4{0.f, 0.f, 0.f, 0.f};
  bf16x8 aF[2], bF[4];

  KLOOP_BODY

  // epilogue: a = silu(gate+b1g) * (lin+b1l+1) * p -> bf16
#pragma unroll
  for (int j = 0; j < 2; ++j) {
    int cf = c0 + wn * 32 + j * 16 + lrow;
    float gb = b1[e * 2 * F_DIM + cf];
    float lb = b1[e * 2 * F_DIM + F_DIM + cf];
#pragma unroll
    for (int i = 0; i < 4; ++i) {
      int trow = tokBase + wm * 64 + i * 16 + lkhi * 4;
#pragma unroll
      for (int r = 0; r < 4; ++r) {
        float g = acc[i][j][r] + gb;
        float l = acc[i][j + 2][r] + lb + 1.0f;
        float p = probs[trow + r];
        float sig = 1.0f / (1.0f + __expf(-g));
        abf[(size_t)(trow + r) * F_DIM + cf] = f2bf(g * sig * l * p);
      }
    }
  }
}

// ---------------------------------------------------------------- GEMM2
__global__ __launch_bounds__(1024) void gemm2_8p(
    const u16* __restrict__ abf, const u16* __restrict__ w2t,
    const float* __restrict__ b2, float* __restrict__ out) {
  extern __shared__ char sm[];
  const int tid = threadIdx.x;
  const int lane = tid & 63;
  const int wid = tid >> 6;
  const int wm = wid >> 2, wn = wid & 3;
  const int bid = blockIdx.x;
  const int e = bid & 7;
  const int inner = bid >> 3;
  const int mt = inner >> 2, nt = inner & 3;
  const int tokBase = e * TPE + mt * 256;
  const int h0 = nt * 256;
  const int lrow = lane & 15, lkhi = lane >> 4;

  const u16* aP[2]; const u16* bP[2];
#pragma unroll
  for (int q = 0; q < 2; ++q) {
    int lin = q * 16384 + tid * 16;
    int lg = lin ^ (((lin >> 7) & 7) << 4);
    int row = lg >> 7, kk = (lg & 127) >> 1;
    aP[q] = abf + (size_t)(tokBase + row) * F_DIM + kk;
    bP[q] = w2t + (size_t)(e * H_DIM + h0 + row) * F_DIM + kk;
  }
  const int aRowBase = (wm * 64 + lrow) * 128;
  const int bRowBase = (wn * 64 + lrow) * 128;
  int koff[2];
#pragma unroll
  for (int ks = 0; ks < 2; ++ks)
    koff[ks] = ((ks << 6) | (lkhi << 4)) ^ ((lane & 7) << 4);

  f32x4 acc[4][4];
#pragma unroll
  for (int i = 0; i < 4; ++i)
#pragma unroll
    for (int j = 0; j < 4; ++j) acc[i][j] = f32x4{0.f, 0.f, 0.f, 0.f};
  bf16x8 aF[2], bF[4];

  KLOOP_BODY

#pragma unroll
  for (int j = 0; j < 4; ++j) {
    int h = h0 + wn * 64 + j * 16 + lrow;
    float bb = b2[e * H_DIM + h];
#pragma unroll
    for (int i = 0; i < 4; ++i) {
      int trow = tokBase + wm * 64 + i * 16 + lkhi * 4;
#pragma unroll
      for (int r = 0; r < 4; ++r)
        out[(size_t)(trow + r) * H_DIM + h] = acc[i][j][r] + bb;
    }
  }
}

// ---------------------------------------------------------------- launch
extern "C" void kernel_launch(void* const* d_in, const int* in_sizes, int n_in,
                              void* d_out, int out_size, void* d_ws,
                              size_t ws_size, hipStream_t stream) {
  const float* x     = (const float*)d_in[0];
  // d_in[1] tokens_per_expert: uniform (T/E) by construction, unused
  const float* probs = (const float*)d_in[2];
  const float* W1    = (const float*)d_in[3];
  const float* b1    = (const float*)d_in[4];
  const float* W2    = (const float*)d_in[5];
  const float* b2    = (const float*)d_in[6];
  float* out = (float*)d_out;

  // workspace: xbf[T,H] 32MB | w1t[E,2F,H] 32MB | w2t[E,H,F] 16MB | abf 32MB
  if (ws_size < 117440512u) return;
  char* ws = (char*)d_ws;
  u16* xbf = (u16*)(ws);
  u16* w1t = (u16*)(ws + 33554432);
  u16* w2t = (u16*)(ws + 67108864);
  u16* abf = (u16*)(ws + 83886080);

  (void)hipFuncSetAttribute(reinterpret_cast<const void*>(gemm1_8p),
                            hipFuncAttributeMaxDynamicSharedMemorySize, 131072);
  (void)hipFuncSetAttribute(reinterpret_cast<const void*>(gemm2_8p),
                            hipFuncAttributeMaxDynamicSharedMemorySize, 131072);

  prep_all<<<7168, 256, 0, stream>>>(x, W1, W2, xbf, w1t, w2t);
  gemm1_8p<<<E_NUM * 8 * 8, 1024, 131072, stream>>>(xbf, w1t, b1, probs, abf);
  gemm2_8p<<<E_NUM * 8 * 4, 1024, 131072, stream>>>(abf, w2t, b2, out);
}

// Round 13
// 152.239 us; speedup vs baseline: 1.0999x; 1.0999x over previous
//
#include <hip/hip_runtime.h>
#include <hip/hip_bf16.h>
#include <stdint.h>

// SequentialMLP: E=8, H=1024, F=1024, T=16384, Tpe=2048
#define T_TOK 16384
#define H_DIM 1024
#define F_DIM 1024
#define E_NUM 8
#define TPE   2048

typedef unsigned short u16;
typedef __attribute__((ext_vector_type(8))) short bf16x8;   // 8 bf16 (4 VGPRs)
typedef __attribute__((ext_vector_type(4))) float f32x4;    // MFMA accumulator
typedef __attribute__((ext_vector_type(8))) u16 u16x8;

__device__ __forceinline__ u16 f2bf(float x) {
  unsigned int u = __float_as_uint(x);
  u = (u + 0x7fffu + ((u >> 16) & 1u)) >> 16;   // RNE
  return (u16)u;
}

// async global->LDS, 16B per lane. LDS dest = wave-uniform base + lane*16.
#define GLD16(gp, lp)                                                          \
  __builtin_amdgcn_global_load_lds(                                            \
      (const __attribute__((address_space(1))) void*)(gp),                     \
      (__attribute__((address_space(3))) void*)(lp), 16, 0, 0)

#define VMW(N) asm volatile("s_waitcnt vmcnt(" #N ")" ::: "memory");

// ================================================================= prep pass
// ROUND-13: pipelined transpose (r12 lesson: LDS required for coalesced
// writes; r10 lesson: 1-tile-per-block is latency-bound). 64x64-f32 tiles,
// 4 tiles/block, double-buffered 2x16KB LDS, gload_lds staging with counted
// vmcnt {4,6,6,2} (stores counted; queue walk in session notes).
// Swizzle byte ^= ((byte>>11)&7)<<4 (involution; row bits 3-5 into 16B slot):
//  - staging: inverse-swizzled GLOBAL source, linear LDS dest (rule 21)
//  - transposed read (r=c*8+i, o): bank = o ^ 4c, o/c lane-bit-disjoint -> 2-way
//  - writes: per instr 8 out-rows x 128B contiguous runs.
// Blocks: [0,1024) x-cvt (grid-stride, no LDS) | [1024,2048) W1 | [2048,2560) W2.
__global__ __launch_bounds__(256) void prep_all(
    const float* __restrict__ x, const float* __restrict__ W1,
    const float* __restrict__ W2, u16* __restrict__ xbf,
    u16* __restrict__ w1t, u16* __restrict__ w2t) {
  __shared__ char lds[32768];
  const int bid = blockIdx.x;
  const int t = threadIdx.x;

  if (bid < 1024) {
    // cvt: 4 iterations x 16 f32/thread, block-contiguous 16KB chunks
#pragma unroll
    for (int it = 0; it < 4; ++it) {
      size_t base = ((size_t)it * 1024 + bid) * 4096 + (size_t)t * 16;
      const float4* s = (const float4*)(x + base);
      float4 v0 = s[0], v1 = s[1], v2 = s[2], v3 = s[3];
      u16x8 o0, o1;
      o0[0] = f2bf(v0.x); o0[1] = f2bf(v0.y); o0[2] = f2bf(v0.z); o0[3] = f2bf(v0.w);
      o0[4] = f2bf(v1.x); o0[5] = f2bf(v1.y); o0[6] = f2bf(v1.z); o0[7] = f2bf(v1.w);
      o1[0] = f2bf(v2.x); o1[1] = f2bf(v2.y); o1[2] = f2bf(v2.z); o1[3] = f2bf(v2.w);
      o1[4] = f2bf(v3.x); o1[5] = f2bf(v3.y); o1[6] = f2bf(v3.z); o1[7] = f2bf(v3.w);
      *(u16x8*)(xbf + base) = o0;
      *(u16x8*)(xbf + base + 8) = o1;
    }
    return;
  }

  // ---- transpose: 4 consecutive 64x64 tiles per block ----
  const float* src; u16* dst; int RR, CC, tbase;
  if (bid < 2048) { src = W1; dst = w1t; RR = H_DIM; CC = 2 * F_DIM; tbase = (bid - 1024) * 4; }
  else           { src = W2; dst = w2t; RR = F_DIM; CC = H_DIM;     tbase = (bid - 2048) * 4; }
  const int tilesPerE = (RR >> 6) * (CC >> 6);
  const int ctn = CC >> 6;

  const float* sb[4]; u16* db[4];
#pragma unroll
  for (int k = 0; k < 4; ++k) {
    int id = tbase + k;
    int e = id / tilesPerE, rem = id - e * tilesPerE;
    int rt = rem / ctn, ct = rem - rt * ctn;
    sb[k] = src + (size_t)e * RR * CC + (size_t)(rt << 6) * CC + (ct << 6);
    db[k] = dst + (size_t)e * CC * RR + (size_t)(ct << 6) * RR + (rt << 6);
  }

  // stage: 4 x gload_lds/thread, inverse-swizzled global source
#define TSTAGE(buf, k)                                                         \
  _Pragma("unroll") for (int p_ = 0; p_ < 4; ++p_) {                           \
    int lin_ = p_ * 4096 + t * 16;                                             \
    int lg_ = lin_ ^ (((lin_ >> 11) & 7) << 4);                                \
    int row_ = lg_ >> 8, col_ = (lg_ & 255) >> 2;                              \
    GLD16(sb[k] + (size_t)row_ * CC + col_, lds + (buf) * 16384 + lin_);       \
  }

  // process: 2 chunk-tasks/thread (id = t, t+256): o = id>>3 (out row),
  // c = id&7 (8-elem chunk). 8 swizzled scalar reads -> cvt -> 16B store.
#define TPROC(buf, k)                                                          \
  _Pragma("unroll") for (int q_ = 0; q_ < 2; ++q_) {                           \
    int id_ = t + q_ * 256;                                                    \
    int o_ = id_ >> 3, c_ = id_ & 7;                                           \
    u16x8 w_;                                                                  \
    _Pragma("unroll") for (int i_ = 0; i_ < 8; ++i_) {                         \
      float f_ = *(const float*)(lds + (buf) * 16384 + (c_ * 8 + i_) * 256 +   \
                                 ((o_ * 4) ^ (c_ << 4)));                      \
      w_[i_] = f2bf(f_);                                                       \
    }                                                                          \
    *(u16x8*)(db[k] + (size_t)o_ * RR + c_ * 8) = w_;                          \
  }

  TSTAGE(0, 0)                    // Q: L0(4)
  TSTAGE(1, 1)                    // Q: L0 L1 (8)
  VMW(4)                          // L0 done
  __syncthreads();
  TPROC(0, 0)                     // +S0(2)
  __syncthreads();
  TSTAGE(0, 2)                    // Q: L1 S0 L2 (10)
  VMW(6)                          // L1 done
  __syncthreads();
  TPROC(1, 1)                     // +S1
  __syncthreads();
  TSTAGE(1, 3)                    // Q: S0 L2 S1 L3 (<=12)
  VMW(6)                          // S0,L2 done
  __syncthreads();
  TPROC(0, 2)                     // +S2
  __syncthreads();
  VMW(2)                          // S1,L3 done
  __syncthreads();
  TPROC(1, 3)
#undef TSTAGE
#undef TPROC
}

// ====================================================== 256x256 GEMM, 16 waves
// r11 version unchanged (best measured total; GEMM schedule family closed).
// BM=BN=256 / BK=64 / 128KB dbuf LDS, 1024 threads (16 waves, 4Mx4N).
// Ledger: prologue B0(2) A0(2) B1(2) -> vmcnt(2), barrier;
// loop p0: A1q0  p1: A1q1  p3: B0'(2)+vmcnt(2)  p4: A0'q0  p5: A0'q1
// p7: B1'(2)+vmcnt(2). Swizzle byte ^= ((row&7)<<4) via inverse-swizzled
// global source (linear LDS dest, rule 21) + swizzled ds_read offset.

#define DSA2(b, h, ks)                                                         \
  _Pragma("unroll") for (int m2_ = 0; m2_ < 2; ++m2_)                          \
      aF[m2_] = *(const bf16x8*)(sm + (b) * 32768 + aRowBase +                 \
                                 ((h) * 2 + m2_) * 2048 + koff[ks]);

#define DSB4(b, ks)                                                            \
  _Pragma("unroll") for (int n_ = 0; n_ < 4; ++n_)                             \
      bF[n_] = *(const bf16x8*)(sm + 65536 + (b) * 32768 + bRowBase +          \
                                n_ * 2048 + koff[ks]);

#define MFMAP(h)                                                               \
  _Pragma("unroll") for (int n_ = 0; n_ < 4; ++n_)                             \
  _Pragma("unroll") for (int m2_ = 0; m2_ < 2; ++m2_)                          \
      acc[(h) * 2 + m2_][n_] = __builtin_amdgcn_mfma_f32_16x16x32_bf16(        \
          aF[m2_], bF[n_], acc[(h) * 2 + m2_][n_], 0, 0, 0);

#define PF_A(db, q, d) GLD16(aP[q] + (d), sm + (db) * 32768 + (q) * 16384 + tid * 16)
#define PF_B(db, q, d) GLD16(bP[q] + (d), sm + 65536 + (db) * 32768 + (q) * 16384 + tid * 16)

#define PHASEK(b, ks, h, PFC, WTC)                                             \
  do {                                                                         \
    DSA2(b, h, ks);                                                            \
    if ((h) == 0) { DSB4(b, ks); }                                             \
    PFC                                                                        \
    __builtin_amdgcn_s_setprio(1);                                             \
    MFMAP(h);                                                                  \
    __builtin_amdgcn_s_setprio(0);                                             \
    WTC                                                                        \
    __builtin_amdgcn_s_barrier();                                              \
  } while (0)

#define KLOOP_BODY                                                             \
  PF_B(0, 0, 0); PF_B(0, 1, 0);                                                \
  PF_A(0, 0, 0); PF_A(0, 1, 0);                                                \
  PF_B(1, 0, 64); PF_B(1, 1, 64);                                              \
  VMW(2)                                                                       \
  __builtin_amdgcn_s_barrier();                                                \
  for (int it = 0; it < 7; ++it) {                                             \
    PHASEK(0, 0, 0, PF_A(1, 0, 64);, );                                        \
    PHASEK(0, 0, 1, PF_A(1, 1, 64);, );                                        \
    PHASEK(0, 1, 0, , );                                                       \
    PHASEK(0, 1, 1, PF_B(0, 0, 128); PF_B(0, 1, 128);, VMW(2));                \
    PHASEK(1, 0, 0, PF_A(0, 0, 128);, );                                       \
    PHASEK(1, 0, 1, PF_A(0, 1, 128);, );                                       \
    PHASEK(1, 1, 0, , );                                                       \
    PHASEK(1, 1, 1, PF_B(1, 0, 192); PF_B(1, 1, 192);, VMW(2));                \
    _Pragma("unroll") for (int q_ = 0; q_ < 2; ++q_) {                         \
      aP[q_] += 128; bP[q_] += 128;                                            \
    }                                                                          \
  }                                                                            \
  PHASEK(0, 0, 0, PF_A(1, 0, 64);, );                                          \
  PHASEK(0, 0, 1, PF_A(1, 1, 64);, );                                          \
  PHASEK(0, 1, 0, , );                                                         \
  PHASEK(0, 1, 1, , VMW(0));                                                   \
  PHASEK(1, 0, 0, , );                                                         \
  PHASEK(1, 0, 1, , );                                                         \
  PHASEK(1, 1, 0, , );                                                         \
  PHASEK(1, 1, 1, , );

// ---------------------------------------------------------------- GEMM1+GLU
__global__ __launch_bounds__(1024) void gemm1_8p(
    const u16* __restrict__ xbf, const u16* __restrict__ w1t,
    const float* __restrict__ b1, const float* __restrict__ probs,
    u16* __restrict__ abf) {
  extern __shared__ char sm[];
  const int tid = threadIdx.x;
  const int lane = tid & 63;
  const int wid = tid >> 6;               // 0..15
  const int wm = wid >> 2, wn = wid & 3;  // 4x4 wave grid, wave tile 64x64
  const int bid = blockIdx.x;
  const int e = bid & 7;          // expert -> XCD pinning (round-robin bid%8)
  const int inner = bid >> 3;
  const int mt = inner >> 3, ct = inner & 7;
  const int tokBase = e * TPE + mt * 256;
  const int c0 = ct * 128;
  const int lrow = lane & 15, lkhi = lane >> 4;

  const u16* aP[2]; const u16* bP[2];
#pragma unroll
  for (int q = 0; q < 2; ++q) {
    int lin = q * 16384 + tid * 16;
    int lg = lin ^ (((lin >> 7) & 7) << 4);   // inverse swizzle (involution)
    int row = lg >> 7, kk = (lg & 127) >> 1;
    aP[q] = xbf + (size_t)(tokBase + row) * H_DIM + kk;
    // B row nn: alternate 32-blocks gate/lin so each wave owns matching pairs
    int col = (((row >> 5) & 1) << 10) + c0 + ((row >> 6) << 5) + (row & 31);
    bP[q] = w1t + (size_t)(e * 2 * F_DIM + col) * H_DIM + kk;
  }
  const int aRowBase = (wm * 64 + lrow) * 128;
  const int bRowBase = (wn * 64 + lrow) * 128;
  int koff[2];
#pragma unroll
  for (int ks = 0; ks < 2; ++ks)
    koff[ks] = ((ks << 6) | (lkhi << 4)) ^ ((lane & 7) << 4);

  f32x4 acc[4][4];
#pragma unroll
  for (int i = 0; i < 4; ++i)
#pragma unroll
    for (int j = 0; j < 4; ++j) acc[i][j] = f32x4{0.f, 0.f, 0.f, 0.f};
  bf16x8 aF[2], bF[4];

  KLOOP_BODY

  // epilogue: a = silu(gate+b1g) * (lin+b1l+1) * p -> bf16
#pragma unroll
  for (int j = 0; j < 2; ++j) {
    int cf = c0 + wn * 32 + j * 16 + lrow;
    float gb = b1[e * 2 * F_DIM + cf];
    float lb = b1[e * 2 * F_DIM + F_DIM + cf];
#pragma unroll
    for (int i = 0; i < 4; ++i) {
      int trow = tokBase + wm * 64 + i * 16 + lkhi * 4;
#pragma unroll
      for (int r = 0; r < 4; ++r) {
        float g = acc[i][j][r] + gb;
        float l = acc[i][j + 2][r] + lb + 1.0f;
        float p = probs[trow + r];
        float sig = 1.0f / (1.0f + __expf(-g));
        abf[(size_t)(trow + r) * F_DIM + cf] = f2bf(g * sig * l * p);
      }
    }
  }
}

// ---------------------------------------------------------------- GEMM2
__global__ __launch_bounds__(1024) void gemm2_8p(
    const u16* __restrict__ abf, const u16* __restrict__ w2t,
    const float* __restrict__ b2, float* __restrict__ out) {
  extern __shared__ char sm[];
  const int tid = threadIdx.x;
  const int lane = tid & 63;
  const int wid = tid >> 6;
  const int wm = wid >> 2, wn = wid & 3;
  const int bid = blockIdx.x;
  const int e = bid & 7;
  const int inner = bid >> 3;
  const int mt = inner >> 2, nt = inner & 3;
  const int tokBase = e * TPE + mt * 256;
  const int h0 = nt * 256;
  const int lrow = lane & 15, lkhi = lane >> 4;

  const u16* aP[2]; const u16* bP[2];
#pragma unroll
  for (int q = 0; q < 2; ++q) {
    int lin = q * 16384 + tid * 16;
    int lg = lin ^ (((lin >> 7) & 7) << 4);
    int row = lg >> 7, kk = (lg & 127) >> 1;
    aP[q] = abf + (size_t)(tokBase + row) * F_DIM + kk;
    bP[q] = w2t + (size_t)(e * H_DIM + h0 + row) * F_DIM + kk;
  }
  const int aRowBase = (wm * 64 + lrow) * 128;
  const int bRowBase = (wn * 64 + lrow) * 128;
  int koff[2];
#pragma unroll
  for (int ks = 0; ks < 2; ++ks)
    koff[ks] = ((ks << 6) | (lkhi << 4)) ^ ((lane & 7) << 4);

  f32x4 acc[4][4];
#pragma unroll
  for (int i = 0; i < 4; ++i)
#pragma unroll
    for (int j = 0; j < 4; ++j) acc[i][j] = f32x4{0.f, 0.f, 0.f, 0.f};
  bf16x8 aF[2], bF[4];

  KLOOP_BODY

#pragma unroll
  for (int j = 0; j < 4; ++j) {
    int h = h0 + wn * 64 + j * 16 + lrow;
    float bb = b2[e * H_DIM + h];
#pragma unroll
    for (int i = 0; i < 4; ++i) {
      int trow = tokBase + wm * 64 + i * 16 + lkhi * 4;
#pragma unroll
      for (int r = 0; r < 4; ++r)
        out[(size_t)(trow + r) * H_DIM + h] = acc[i][j][r] + bb;
    }
  }
}

// ---------------------------------------------------------------- launch
extern "C" void kernel_launch(void* const* d_in, const int* in_sizes, int n_in,
                              void* d_out, int out_size, void* d_ws,
                              size_t ws_size, hipStream_t stream) {
  const float* x     = (const float*)d_in[0];
  // d_in[1] tokens_per_expert: uniform (T/E) by construction, unused
  const float* probs = (const float*)d_in[2];
  const float* W1    = (const float*)d_in[3];
  const float* b1    = (const float*)d_in[4];
  const float* W2    = (const float*)d_in[5];
  const float* b2    = (const float*)d_in[6];
  float* out = (float*)d_out;

  // workspace: xbf[T,H] 32MB | w1t[E,2F,H] 32MB | w2t[E,H,F] 16MB | abf 32MB
  if (ws_size < 117440512u) return;
  char* ws = (char*)d_ws;
  u16* xbf = (u16*)(ws);
  u16* w1t = (u16*)(ws + 33554432);
  u16* w2t = (u16*)(ws + 67108864);
  u16* abf = (u16*)(ws + 83886080);

  (void)hipFuncSetAttribute(reinterpret_cast<const void*>(gemm1_8p),
                            hipFuncAttributeMaxDynamicSharedMemorySize, 131072);
  (void)hipFuncSetAttribute(reinterpret_cast<const void*>(gemm2_8p),
                            hipFuncAttributeMaxDynamicSharedMemorySize, 131072);

  prep_all<<<2560, 256, 0, stream>>>(x, W1, W2, xbf, w1t, w2t);
  gemm1_8p<<<E_NUM * 8 * 8, 1024, 131072, stream>>>(xbf, w1t, b1, probs, abf);
  gemm2_8p<<<E_NUM * 8 * 4, 1024, 131072, stream>>>(abf, w2t, b2, out);
}

// Round 14
// 148.751 us; speedup vs baseline: 1.1256x; 1.0234x over previous
//
#include <hip/hip_runtime.h>
#include <hip/hip_bf16.h>
#include <stdint.h>

// SequentialMLP: E=8, H=1024, F=1024, T=16384, Tpe=2048
#define T_TOK 16384
#define H_DIM 1024
#define F_DIM 1024
#define E_NUM 8
#define TPE   2048

typedef unsigned short u16;
typedef __attribute__((ext_vector_type(8))) short bf16x8;   // 8 bf16 (4 VGPRs)
typedef __attribute__((ext_vector_type(4))) float f32x4;    // MFMA accumulator
typedef __attribute__((ext_vector_type(8))) u16 u16x8;

__device__ __forceinline__ u16 f2bf(float x) {
  unsigned int u = __float_as_uint(x);
  u = (u + 0x7fffu + ((u >> 16) & 1u)) >> 16;   // RNE
  return (u16)u;
}

// async global->LDS, 16B per lane. LDS dest = wave-uniform base + lane*16.
#define GLD16(gp, lp)                                                          \
  __builtin_amdgcn_global_load_lds(                                            \
      (const __attribute__((address_space(1))) void*)(gp),                     \
      (__attribute__((address_space(3))) void*)(lp), 16, 0, 0)

#define VMW(N) asm volatile("s_waitcnt vmcnt(" #N ")" ::: "memory");

// ================================================================= prep pass
// ROUND-14: r9 prep restored (timed-best prep family). 64x64 tiles,
// tile[64][65] = 16.6KB static LDS -> 8 blocks/CU (thread-capped, FULL
// occupancy) for both cvt and transpose roles. r10/r13's 32-33KB variants
// halved occupancy (4-5 blocks/CU) with no timed gain.
// Blocks: [0,4096) x-cvt | [4096,8192) W1 tiles | [8192,10240) W2 tiles.
__global__ __launch_bounds__(256) void prep_all(
    const float* __restrict__ x, const float* __restrict__ W1,
    const float* __restrict__ W2, u16* __restrict__ xbf,
    u16* __restrict__ w1t, u16* __restrict__ w2t) {
  __shared__ float tile[64][65];
  const int bid = blockIdx.x;
  const int t = threadIdx.x;

  if (bid < 4096) {
    // flat cvt: block covers f32 [bid*4096, +4096); thread: 16 consecutive
    size_t base = (size_t)bid * 4096 + (size_t)t * 16;
    const float4* s = (const float4*)(x + base);
    float4 v0 = s[0], v1 = s[1], v2 = s[2], v3 = s[3];
    u16x8 o0, o1;
    o0[0] = f2bf(v0.x); o0[1] = f2bf(v0.y); o0[2] = f2bf(v0.z); o0[3] = f2bf(v0.w);
    o0[4] = f2bf(v1.x); o0[5] = f2bf(v1.y); o0[6] = f2bf(v1.z); o0[7] = f2bf(v1.w);
    o1[0] = f2bf(v2.x); o1[1] = f2bf(v2.y); o1[2] = f2bf(v2.z); o1[3] = f2bf(v2.w);
    o1[4] = f2bf(v3.x); o1[5] = f2bf(v3.y); o1[6] = f2bf(v3.z); o1[7] = f2bf(v3.w);
    *(u16x8*)(xbf + base) = o0;
    *(u16x8*)(xbf + base + 8) = o1;
    return;
  }

  const float* src; u16* dst; int R, C, e, rt, ct;
  if (bid < 8192) {
    int id = bid - 4096;
    e = id >> 9; int r2 = id & 511; rt = r2 >> 5; ct = r2 & 31;
    src = W1; dst = w1t; R = H_DIM; C = 2 * F_DIM;
  } else {
    int id = bid - 8192;
    e = id >> 8; int r2 = id & 255; rt = r2 >> 4; ct = r2 & 15;
    src = W2; dst = w2t; R = F_DIM; C = H_DIM;
  }
  const float* s = src + (size_t)e * R * C + (size_t)(rt << 6) * C + (ct << 6);
  int lr = t >> 4, lc = (t & 15) << 2;
#pragma unroll
  for (int i = 0; i < 4; i++) {
    float4 v = *(const float4*)(s + (size_t)(lr + i * 16) * C + lc);
    tile[lr + i * 16][lc + 0] = v.x;
    tile[lr + i * 16][lc + 1] = v.y;
    tile[lr + i * 16][lc + 2] = v.z;
    tile[lr + i * 16][lc + 3] = v.w;
  }
  __syncthreads();
  u16* d = dst + (size_t)e * C * R + (size_t)(ct << 6) * R + (rt << 6);
  int orow = t >> 2, ok = (t & 3) << 4;
  u16x8 o0, o1;
#pragma unroll
  for (int i = 0; i < 8; i++) o0[i] = f2bf(tile[ok + i][orow]);
#pragma unroll
  for (int i = 0; i < 8; i++) o1[i] = f2bf(tile[ok + 8 + i][orow]);
  *(u16x8*)(d + (size_t)orow * R + ok) = o0;
  *(u16x8*)(d + (size_t)orow * R + ok + 8) = o1;
}

// ====================================================== 256x256 GEMM, 16 waves
// r11 version unchanged (best measured total; GEMM schedule family closed).
// BM=BN=256 / BK=64 / 128KB dbuf LDS, 1024 threads (16 waves, 4Mx4N).
// Ledger: prologue B0(2) A0(2) B1(2) -> vmcnt(2), barrier;
// loop p0: A1q0  p1: A1q1  p3: B0'(2)+vmcnt(2)  p4: A0'q0  p5: A0'q1
// p7: B1'(2)+vmcnt(2). Swizzle byte ^= ((row&7)<<4) via inverse-swizzled
// global source (linear LDS dest, rule 21) + swizzled ds_read offset.

#define DSA2(b, h, ks)                                                         \
  _Pragma("unroll") for (int m2_ = 0; m2_ < 2; ++m2_)                          \
      aF[m2_] = *(const bf16x8*)(sm + (b) * 32768 + aRowBase +                 \
                                 ((h) * 2 + m2_) * 2048 + koff[ks]);

#define DSB4(b, ks)                                                            \
  _Pragma("unroll") for (int n_ = 0; n_ < 4; ++n_)                             \
      bF[n_] = *(const bf16x8*)(sm + 65536 + (b) * 32768 + bRowBase +          \
                                n_ * 2048 + koff[ks]);

#define MFMAP(h)                                                               \
  _Pragma("unroll") for (int n_ = 0; n_ < 4; ++n_)                             \
  _Pragma("unroll") for (int m2_ = 0; m2_ < 2; ++m2_)                          \
      acc[(h) * 2 + m2_][n_] = __builtin_amdgcn_mfma_f32_16x16x32_bf16(        \
          aF[m2_], bF[n_], acc[(h) * 2 + m2_][n_], 0, 0, 0);

#define PF_A(db, q, d) GLD16(aP[q] + (d), sm + (db) * 32768 + (q) * 16384 + tid * 16)
#define PF_B(db, q, d) GLD16(bP[q] + (d), sm + 65536 + (db) * 32768 + (q) * 16384 + tid * 16)

#define PHASEK(b, ks, h, PFC, WTC)                                             \
  do {                                                                         \
    DSA2(b, h, ks);                                                            \
    if ((h) == 0) { DSB4(b, ks); }                                             \
    PFC                                                                        \
    __builtin_amdgcn_s_setprio(1);                                             \
    MFMAP(h);                                                                  \
    __builtin_amdgcn_s_setprio(0);                                             \
    WTC                                                                        \
    __builtin_amdgcn_s_barrier();                                              \
  } while (0)

#define KLOOP_BODY                                                             \
  PF_B(0, 0, 0); PF_B(0, 1, 0);                                                \
  PF_A(0, 0, 0); PF_A(0, 1, 0);                                                \
  PF_B(1, 0, 64); PF_B(1, 1, 64);                                              \
  VMW(2)                                                                       \
  __builtin_amdgcn_s_barrier();                                                \
  for (int it = 0; it < 7; ++it) {                                             \
    PHASEK(0, 0, 0, PF_A(1, 0, 64);, );                                        \
    PHASEK(0, 0, 1, PF_A(1, 1, 64);, );                                        \
    PHASEK(0, 1, 0, , );                                                       \
    PHASEK(0, 1, 1, PF_B(0, 0, 128); PF_B(0, 1, 128);, VMW(2));                \
    PHASEK(1, 0, 0, PF_A(0, 0, 128);, );                                       \
    PHASEK(1, 0, 1, PF_A(0, 1, 128);, );                                       \
    PHASEK(1, 1, 0, , );                                                       \
    PHASEK(1, 1, 1, PF_B(1, 0, 192); PF_B(1, 1, 192);, VMW(2));                \
    _Pragma("unroll") for (int q_ = 0; q_ < 2; ++q_) {                         \
      aP[q_] += 128; bP[q_] += 128;                                            \
    }                                                                          \
  }                                                                            \
  PHASEK(0, 0, 0, PF_A(1, 0, 64);, );                                          \
  PHASEK(0, 0, 1, PF_A(1, 1, 64);, );                                          \
  PHASEK(0, 1, 0, , );                                                         \
  PHASEK(0, 1, 1, , VMW(0));                                                   \
  PHASEK(1, 0, 0, , );                                                         \
  PHASEK(1, 0, 1, , );                                                         \
  PHASEK(1, 1, 0, , );                                                         \
  PHASEK(1, 1, 1, , );

// ---------------------------------------------------------------- GEMM1+GLU
__global__ __launch_bounds__(1024) void gemm1_8p(
    const u16* __restrict__ xbf, const u16* __restrict__ w1t,
    const float* __restrict__ b1, const float* __restrict__ probs,
    u16* __restrict__ abf) {
  extern __shared__ char sm[];
  const int tid = threadIdx.x;
  const int lane = tid & 63;
  const int wid = tid >> 6;               // 0..15
  const int wm = wid >> 2, wn = wid & 3;  // 4x4 wave grid, wave tile 64x64
  const int bid = blockIdx.x;
  const int e = bid & 7;          // expert -> XCD pinning (round-robin bid%8)
  const int inner = bid >> 3;
  const int mt = inner >> 3, ct = inner & 7;
  const int tokBase = e * TPE + mt * 256;
  const int c0 = ct * 128;
  const int lrow = lane & 15, lkhi = lane >> 4;

  const u16* aP[2]; const u16* bP[2];
#pragma unroll
  for (int q = 0; q < 2; ++q) {
    int lin = q * 16384 + tid * 16;
    int lg = lin ^ (((lin >> 7) & 7) << 4);   // inverse swizzle (involution)
    int row = lg >> 7, kk = (lg & 127) >> 1;
    aP[q] = xbf + (size_t)(tokBase + row) * H_DIM + kk;
    // B row nn: alternate 32-blocks gate/lin so each wave owns matching pairs
    int col = (((row >> 5) & 1) << 10) + c0 + ((row >> 6) << 5) + (row & 31);
    bP[q] = w1t + (size_t)(e * 2 * F_DIM + col) * H_DIM + kk;
  }
  const int aRowBase = (wm * 64 + lrow) * 128;
  const int bRowBase = (wn * 64 + lrow) * 128;
  int koff[2];
#pragma unroll
  for (int ks = 0; ks < 2; ++ks)
    koff[ks] = ((ks << 6) | (lkhi << 4)) ^ ((lane & 7) << 4);

  f32x4 acc[4][4];
#pragma unroll
  for (int i = 0; i < 4; ++i)
#pragma unroll
    for (int j = 0; j < 4; ++j) acc[i][j] = f32x4{0.f, 0.f, 0.f, 0.f};
  bf16x8 aF[2], bF[4];

  KLOOP_BODY

  // epilogue: a = silu(gate+b1g) * (lin+b1l+1) * p -> bf16
#pragma unroll
  for (int j = 0; j < 2; ++j) {
    int cf = c0 + wn * 32 + j * 16 + lrow;
    float gb = b1[e * 2 * F_DIM + cf];
    float lb = b1[e * 2 * F_DIM + F_DIM + cf];
#pragma unroll
    for (int i = 0; i < 4; ++i) {
      int trow = tokBase + wm * 64 + i * 16 + lkhi * 4;
#pragma unroll
      for (int r = 0; r < 4; ++r) {
        float g = acc[i][j][r] + gb;
        float l = acc[i][j + 2][r] + lb + 1.0f;
        float p = probs[trow + r];
        float sig = 1.0f / (1.0f + __expf(-g));
        abf[(size_t)(trow + r) * F_DIM + cf] = f2bf(g * sig * l * p);
      }
    }
  }
}

// ---------------------------------------------------------------- GEMM2
__global__ __launch_bounds__(1024) void gemm2_8p(
    const u16* __restrict__ abf, const u16* __restrict__ w2t,
    const float* __restrict__ b2, float* __restrict__ out) {
  extern __shared__ char sm[];
  const int tid = threadIdx.x;
  const int lane = tid & 63;
  const int wid = tid >> 6;
  const int wm = wid >> 2, wn = wid & 3;
  const int bid = blockIdx.x;
  const int e = bid & 7;
  const int inner = bid >> 3;
  const int mt = inner >> 2, nt = inner & 3;
  const int tokBase = e * TPE + mt * 256;
  const int h0 = nt * 256;
  const int lrow = lane & 15, lkhi = lane >> 4;

  const u16* aP[2]; const u16* bP[2];
#pragma unroll
  for (int q = 0; q < 2; ++q) {
    int lin = q * 16384 + tid * 16;
    int lg = lin ^ (((lin >> 7) & 7) << 4);
    int row = lg >> 7, kk = (lg & 127) >> 1;
    aP[q] = abf + (size_t)(tokBase + row) * F_DIM + kk;
    bP[q] = w2t + (size_t)(e * H_DIM + h0 + row) * F_DIM + kk;
  }
  const int aRowBase = (wm * 64 + lrow) * 128;
  const int bRowBase = (wn * 64 + lrow) * 128;
  int koff[2];
#pragma unroll
  for (int ks = 0; ks < 2; ++ks)
    koff[ks] = ((ks << 6) | (lkhi << 4)) ^ ((lane & 7) << 4);

  f32x4 acc[4][4];
#pragma unroll
  for (int i = 0; i < 4; ++i)
#pragma unroll
    for (int j = 0; j < 4; ++j) acc[i][j] = f32x4{0.f, 0.f, 0.f, 0.f};
  bf16x8 aF[2], bF[4];

  KLOOP_BODY

#pragma unroll
  for (int j = 0; j < 4; ++j) {
    int h = h0 + wn * 64 + j * 16 + lrow;
    float bb = b2[e * H_DIM + h];
#pragma unroll
    for (int i = 0; i < 4; ++i) {
      int trow = tokBase + wm * 64 + i * 16 + lkhi * 4;
#pragma unroll
      for (int r = 0; r < 4; ++r)
        out[(size_t)(trow + r) * H_DIM + h] = acc[i][j][r] + bb;
    }
  }
}

// ---------------------------------------------------------------- launch
extern "C" void kernel_launch(void* const* d_in, const int* in_sizes, int n_in,
                              void* d_out, int out_size, void* d_ws,
                              size_t ws_size, hipStream_t stream) {
  const float* x     = (const float*)d_in[0];
  // d_in[1] tokens_per_expert: uniform (T/E) by construction, unused
  const float* probs = (const float*)d_in[2];
  const float* W1    = (const float*)d_in[3];
  const float* b1    = (const float*)d_in[4];
  const float* W2    = (const float*)d_in[5];
  const float* b2    = (const float*)d_in[6];
  float* out = (float*)d_out;

  // workspace: xbf[T,H] 32MB | w1t[E,2F,H] 32MB | w2t[E,H,F] 16MB | abf 32MB
  if (ws_size < 117440512u) return;
  char* ws = (char*)d_ws;
  u16* xbf = (u16*)(ws);
  u16* w1t = (u16*)(ws + 33554432);
  u16* w2t = (u16*)(ws + 67108864);
  u16* abf = (u16*)(ws + 83886080);

  (void)hipFuncSetAttribute(reinterpret_cast<const void*>(gemm1_8p),
                            hipFuncAttributeMaxDynamicSharedMemorySize, 131072);
  (void)hipFuncSetAttribute(reinterpret_cast<const void*>(gemm2_8p),
                            hipFuncAttributeMaxDynamicSharedMemorySize, 131072);

  prep_all<<<10240, 256, 0, stream>>>(x, W1, W2, xbf, w1t, w2t);
  gemm1_8p<<<E_NUM * 8 * 8, 1024, 131072, stream>>>(xbf, w1t, b1, probs, abf);
  gemm2_8p<<<E_NUM * 8 * 4, 1024, 131072, stream>>>(abf, w2t, b2, out);
}